// Round 10
// baseline (294.597 us; speedup 1.0000x reference)
//
#include <hip/hip_runtime.h>
#include <hip/hip_bf16.h>
#include <cstddef>
#include <cstdint>

#define B_     4
#define N_     4096
#define DIM_   1024
#define H_     16
#define DH_    64
#define INNER_ 1024
#define MTOK   (B_ * N_)        // 16384
#define QKVC   (3 * INNER_)
#define NCH    16
#define CHUNK  (N_ / NCH)       // 256

typedef __attribute__((ext_vector_type(8))) short short8;   // 8 bf16 = 4 VGPR
typedef __attribute__((ext_vector_type(4))) float f32x4;    // MFMA acc

__device__ __forceinline__ float elu1(float x) {
    return x > 0.f ? x + 1.f : __expf(x);
}
__device__ __forceinline__ unsigned short f2bf(float f) {
    __hip_bfloat16 h = __float2bfloat16(f);
    return __builtin_bit_cast(unsigned short, h);
}
__device__ __forceinline__ float bf2f(unsigned short u) {
    __hip_bfloat16 h = __builtin_bit_cast(__hip_bfloat16, u);
    return __bfloat162float(h);
}

// async global->LDS, 16B per lane. LDS dest is wave-uniform base + lane*16;
// global source address is per-lane.
__device__ __forceinline__ void gload16(const void* g, void* l) {
    __builtin_amdgcn_global_load_lds(
        (const __attribute__((address_space(1))) unsigned int*)g,
        (__attribute__((address_space(3))) unsigned int*)l, 16, 0, 0);
}

// ---------------------------------------------------------------------------
// Weight prep: blocks 0..3071 transpose-cast Wqkv; 3072..4095 Wout.
// (x cast is fused into GEMM1's A-staging now.)
// ---------------------------------------------------------------------------
__global__ __launch_bounds__(256) void prep_w(
    const float* __restrict__ Wqkv, unsigned short* __restrict__ wqkvT,
    const float* __restrict__ Wout, unsigned short* __restrict__ woutT)
{
    __shared__ float t[32][33];
    const int blk = blockIdx.x;
    const float* src; unsigned short* dst; int R, C, r0, c0;
    if (blk < 3072) {                            // 3072 tiles: 32 x 96
        src = Wqkv; dst = wqkvT; R = DIM_; C = QKVC;
        r0 = (blk & 31) * 32; c0 = (blk >> 5) * 32;
    } else {                                     // 1024 tiles: 32 x 32
        const int id = blk - 3072;
        src = Wout; dst = woutT; R = INNER_; C = INNER_;
        r0 = (id & 31) * 32; c0 = (id >> 5) * 32;
    }
    const int tx = threadIdx.x & 31, ty = threadIdx.x >> 5;   // ty 0..7
#pragma unroll
    for (int i = 0; i < 4; ++i)
        t[ty * 4 + i][tx] = src[(size_t)(r0 + ty * 4 + i) * C + c0 + tx];
    __syncthreads();
#pragma unroll
    for (int i = 0; i < 4; ++i)
        dst[(size_t)(c0 + ty * 4 + i) * R + r0 + tx] = f2bf(t[tx][ty * 4 + i]);
}

// ---------------------------------------------------------------------------
// bf16 MFMA GEMM, 256x256 tile / BK=64 / 8 waves (2Mx4N) / 4-phase K-tiles.
// C[M][N] = A[M][K] @ BT[N][K]^T.
// Round-5-verified structure: 128B LDS rows, 8x16B-slot XOR swizzle
// (phys = log^(row&7)), pre-swizzled staging source, conflict-free
// ds_read_b128; A-frag reads software-pipelined by phase parity; staging for
// t+1 issued at tile prologue; one __syncthreads() boundary per K-tile.
// AF32=1: A is fp32; A-staging is reg-staged (load float4 x2 from the same
//   pre-swizzled source address, f2bf convert, ds_write_b128 to the exact
//   bytes gload16 would write). Loads issue at tile-t prologue BEFORE the B
//   gload16s (in-order vmcnt => cvt's wait leaves B loads in flight);
//   cvt+ds_write after phase 3; boundary __syncthreads gives visibility.
//   Eliminates the standalone x cast pass.
// AF32=0: A staged via gload16 (bf16), as verified.
// EPI 0: fp32 out (+bias).   EPI 1: bf16 out, elu1 applied (q path).
// EPI 3: merged qkv (N=3072). col0 < 1024: q path -> Cv bf16 elu1 (ldc).
//        col0 >= 1024: kv path -> Ckv[ch][tok] transposed bf16 (ld MTOK),
//        mask[tok], elu1 iff global col < 2048 (k half); LDS-bounced.
// Requires M%256==0, N%256==0, K%64==0.
// ---------------------------------------------------------------------------
template<int EPI, int HAS_BIAS, int AF32>
__global__ __launch_bounds__(512, 2) void gemm256(
    const void* __restrict__ Av,            // [M][K] bf16 (AF32=0) / fp32 (=1)
    const unsigned short* __restrict__ BT,  // [N][K] bf16
    void* __restrict__ Cv,
    unsigned short* __restrict__ Ckv,
    const float* __restrict__ bias,
    const int* __restrict__ msk,
    int M, int N, int K, int lda, int ldb, int ldc)
{
    const unsigned short* A  = (const unsigned short*)Av;
    const float*          Af = (const float*)Av;

    // smem[0..1] = A double buffer, smem[2..3] = B double buffer.
    // EPI 3-kv reuses the whole 128 KiB as a 256x256 bf16 transpose bounce.
    __shared__ __align__(16) unsigned short smem[4][256 * 64];

    const int tid = threadIdx.x;
    const int wv  = tid >> 6;        // wave 0..7
    const int ln  = tid & 63;
    const int wr  = wv >> 2;         // 0..1  (M half)
    const int wc  = wv & 3;          // 0..3  (N quarter)

    // T1: bijective XCD-aware block swizzle (8 XCDs)
    const int nwg = gridDim.x;
    int wg = blockIdx.x;
    {
        const int q = nwg >> 3, r = nwg & 7;
        const int xcd = wg & 7, lid = wg >> 3;
        wg = (xcd < r ? xcd * (q + 1) : r * (q + 1) + (xcd - r) * q) + lid;
    }
    const int ncol = N >> 8;
    const int bx = wg % ncol;
    const int by = wg / ncol;
    const int row0 = by << 8;
    const int col0 = bx << 8;

    // staging: lane l covers LDS row base+(l>>3), physical 16B slot (l&7);
    // physical slot s at row r holds logical slot s^(r&7).
    const int l8    = ln >> 3;
    const int sslot = ((ln & 7) ^ l8) << 3;   // elem col offset within BK=64

    const int lr16 = ln & 15;
    const int kc   = ln >> 4;
    const int sw   = lr16 & 7;
    const int soff0 = (kc ^ sw) << 3;          // ks=0 logical slot kc
    const int soff1 = ((4 + kc) ^ sw) << 3;    // ks=1 logical slot 4+kc

    f32x4 acc[8][4];
#pragma unroll
    for (int m = 0; m < 8; ++m)
#pragma unroll
        for (int n = 0; n < 4; ++n) acc[m][n] = f32x4{0.f, 0.f, 0.f, 0.f};

    const int NT = K >> 6;

    // prologue: stage K-tile 0 into buffer 0
    if constexpr (AF32) {
#pragma unroll
        for (int i = 0; i < 4; ++i) {
            const int lr = wv * 32 + i * 8;
            const float* s = &Af[(size_t)(row0 + lr + l8) * lda + sslot];
            const float4 a0 = *reinterpret_cast<const float4*>(s);
            const float4 a1 = *reinterpret_cast<const float4*>(s + 4);
            short8 u;
            u[0] = (short)f2bf(a0.x); u[1] = (short)f2bf(a0.y);
            u[2] = (short)f2bf(a0.z); u[3] = (short)f2bf(a0.w);
            u[4] = (short)f2bf(a1.x); u[5] = (short)f2bf(a1.y);
            u[6] = (short)f2bf(a1.z); u[7] = (short)f2bf(a1.w);
            *reinterpret_cast<short8*>(&smem[0][lr * 64 + ln * 8]) = u;
        }
    } else {
#pragma unroll
        for (int i = 0; i < 4; ++i) {
            const int lr = wv * 32 + i * 8;
            gload16(&A[(size_t)(row0 + lr + l8) * lda + sslot], &smem[0][lr * 64]);
        }
    }
#pragma unroll
    for (int i = 0; i < 4; ++i) {
        const int lr = wv * 32 + i * 8;
        gload16(&BT[(size_t)(col0 + lr + l8) * ldb + sslot], &smem[2][lr * 64]);
    }
    __syncthreads();   // drains vmcnt + lgkm: tile 0 resident

    for (int t = 0; t < NT; ++t) {
        const int cur = t & 1;
        const unsigned short* bufA = smem[cur];
        const unsigned short* bufB = smem[2 + cur];
        short8 bf[4][2];
        short8 af[2][2][2];   // [phase parity][mi][ks]
        float4 ar[4][2];      // AF32: staged fp32 A for tile t+1

        // tile prologue: A fp32 loads for t+1 FIRST (in-order vmcnt: the cvt
        // wait later leaves the B gload16s in flight), then B-frags, phase-0
        // A-frags, and t+1 staging issues.
        if (AF32 && t + 1 < NT) {
            const int k0 = (t + 1) << 6;
#pragma unroll
            for (int i = 0; i < 4; ++i) {
                const int lr = wv * 32 + i * 8;
                const float* s = &Af[(size_t)(row0 + lr + l8) * lda + k0 + sslot];
                ar[i][0] = *reinterpret_cast<const float4*>(s);
                ar[i][1] = *reinterpret_cast<const float4*>(s + 4);
            }
        }
#pragma unroll
        for (int n = 0; n < 4; ++n) {
            const int row = wc * 64 + n * 16 + lr16;
            bf[n][0] = *reinterpret_cast<const short8*>(&bufB[row * 64 + soff0]);
            bf[n][1] = *reinterpret_cast<const short8*>(&bufB[row * 64 + soff1]);
        }
#pragma unroll
        for (int mi = 0; mi < 2; ++mi) {
            const int row = wr * 128 + mi * 16 + lr16;
            af[0][mi][0] = *reinterpret_cast<const short8*>(&bufA[row * 64 + soff0]);
            af[0][mi][1] = *reinterpret_cast<const short8*>(&bufA[row * 64 + soff1]);
        }
        if (t + 1 < NT) {
            const int k0 = (t + 1) << 6;
            unsigned short* nA = smem[cur ^ 1];
            unsigned short* nB = smem[2 + (cur ^ 1)];
#pragma unroll
            for (int i = 0; i < 4; ++i) {
                const int lr = wv * 32 + i * 8;
                if constexpr (!AF32)
                    gload16(&A[(size_t)(row0 + lr + l8) * lda + k0 + sslot],
                            &nA[lr * 64]);
                gload16(&BT[(size_t)(col0 + lr + l8) * ldb + k0 + sslot],
                        &nB[lr * 64]);
            }
        }

#pragma unroll
        for (int p = 0; p < 4; ++p) {
            if (p > 0) __builtin_amdgcn_s_barrier();
            // prefetch next phase's A-frags BEFORE this phase's MFMA:
            // latency hides under the 16-MFMA cluster.
            if (p < 3) {
#pragma unroll
                for (int mi = 0; mi < 2; ++mi) {
                    const int row = wr * 128 + ((p + 1) * 2 + mi) * 16 + lr16;
                    af[(p + 1) & 1][mi][0] =
                        *reinterpret_cast<const short8*>(&bufA[row * 64 + soff0]);
                    af[(p + 1) & 1][mi][1] =
                        *reinterpret_cast<const short8*>(&bufA[row * 64 + soff1]);
                }
            }
            __builtin_amdgcn_s_setprio(1);
#pragma unroll
            for (int mi = 0; mi < 2; ++mi)
#pragma unroll
                for (int n = 0; n < 4; ++n) {
                    acc[p * 2 + mi][n] = __builtin_amdgcn_mfma_f32_16x16x32_bf16(
                        af[p & 1][mi][0], bf[n][0], acc[p * 2 + mi][n], 0, 0, 0);
                    acc[p * 2 + mi][n] = __builtin_amdgcn_mfma_f32_16x16x32_bf16(
                        af[p & 1][mi][1], bf[n][1], acc[p * 2 + mi][n], 0, 0, 0);
                }
            __builtin_amdgcn_s_setprio(0);
        }
        // AF32: convert + ds_write A tile t+1 (loads issued ~4 phases ago);
        // dest buffer cur^1 has no readers during tile t.
        if (AF32 && t + 1 < NT) {
            unsigned short* nA = smem[cur ^ 1];
#pragma unroll
            for (int i = 0; i < 4; ++i) {
                const int lr = wv * 32 + i * 8;
                short8 u;
                u[0] = (short)f2bf(ar[i][0].x); u[1] = (short)f2bf(ar[i][0].y);
                u[2] = (short)f2bf(ar[i][0].z); u[3] = (short)f2bf(ar[i][0].w);
                u[4] = (short)f2bf(ar[i][1].x); u[5] = (short)f2bf(ar[i][1].y);
                u[6] = (short)f2bf(ar[i][1].z); u[7] = (short)f2bf(ar[i][1].w);
                *reinterpret_cast<short8*>(&nA[lr * 64 + ln * 8]) = u;
            }
        }
        __syncthreads();   // boundary: drain staging (issued ~4 phases ago)
    }

    // epilogue: C/D layout col=lane&15, row=(lane>>4)*4+reg
    const int orow = (ln >> 4) << 2;
    const int ocol = ln & 15;

    const bool kvpath = (EPI == 3 && col0 >= 1024);

    if (kvpath) {
        // ---- transposed bf16 out via LDS bounce ----
        // tb[ch][tok] 256x256 bf16, 16B-slot swizzle: phys16 = log16 ^ (ch&7)
        unsigned short* tb = &smem[0][0];
#pragma unroll
        for (int m = 0; m < 8; ++m) {
            const int rrb = wr * 128 + m * 16 + orow;       // local token, %4==0
            const int4 m4 = *reinterpret_cast<const int4*>(&msk[row0 + rrb]);
            int mv[4] = { m4.x, m4.y, m4.z, m4.w };
            const int slot16 = rrb >> 3, half = (rrb >> 2) & 1;
#pragma unroll
            for (int n = 0; n < 4; ++n) {
                const int chl = wc * 64 + n * 16 + ocol;    // local channel
                const bool isk = (col0 + chl) < 2048;
                ushort4 st;
#pragma unroll
                for (int r2 = 0; r2 < 4; ++r2) {
                    float o = acc[m][n][r2];
                    o = mv[r2] ? (isk ? elu1(o) : o) : 0.f;
                    ((unsigned short*)&st)[r2] = f2bf(o);
                }
                *reinterpret_cast<ushort4*>(
                    &tb[chl * 256 + ((slot16 ^ (chl & 7)) << 3) + half * 4]) = st;
            }
        }
        __syncthreads();
#pragma unroll
        for (int i = 0; i < 16; ++i) {
            const int idx = i * 512 + tid;      // 8192 16B slots
            const int ch = idx >> 5;
            const int sl = idx & 31;
            const short8 v = *reinterpret_cast<const short8*>(
                &tb[ch * 256 + ((sl ^ (ch & 7)) << 3)]);
            *reinterpret_cast<short8*>(
                &Ckv[(size_t)(col0 - 1024 + ch) * MTOK + row0 + sl * 8]) = v;
        }
    } else {
#pragma unroll
        for (int m = 0; m < 8; ++m) {
            const int rrb = row0 + wr * 128 + m * 16 + orow;
#pragma unroll
            for (int n = 0; n < 4; ++n) {
                const int c = col0 + wc * 64 + n * 16 + ocol;
                float bv = 0.f;
                if constexpr (HAS_BIAS) bv = bias[c];
#pragma unroll
                for (int r2 = 0; r2 < 4; ++r2) {
                    const int rr = rrb + r2;
                    float o = acc[m][n][r2] + bv;
                    if constexpr (EPI == 1 || EPI == 3) {
                        o = elu1(o);
                        ((unsigned short*)Cv)[(size_t)rr * ldc + c] = f2bf(o);
                    } else {
                        ((float*)Cv)[(size_t)rr * ldc + c] = o;
                    }
                }
            }
        }
    }
}

// ---------------------------------------------------------------------------
// Phase A (MFMA): per (b,h,chunk) partial kv[64][64] and ksum[64].
// Inputs already elu'd (k) and masked (k,v), in kvT [2048 ch][16384 tok] bf16:
// k channel = h*64+d, v channel = 1024+h*64+e.
// ---------------------------------------------------------------------------
__global__ __launch_bounds__(256) void kv_partial(
    const unsigned short* __restrict__ kvT, float* __restrict__ part)
{
    const int bh = blockIdx.x;        // 0..63
    const int ch = blockIdx.y;        // 0..15
    const int b = bh / H_, h = bh % H_;
    const int tok0 = b * N_ + ch * CHUNK;

    __shared__ __align__(16) unsigned short kt[64 * 64];
    __shared__ __align__(16) unsigned short vt[64 * 64];
    __shared__ float ksr[4][64];

    const int tid = threadIdx.x;
    const int wv = tid >> 6, ln = tid & 63;
    const int wr = wv >> 1, wc = wv & 1;      // 2x2 quadrants of 64x64
    const int l8 = ln >> 3;
    const int sslot = ((ln & 7) ^ l8) << 3;
    const int lr16 = ln & 15;
    const int kc = ln >> 4;
    const int sw = lr16 & 7;

    const size_t krow = (size_t)(h * 64) * MTOK;
    const size_t vrow = (size_t)(1024 + h * 64) * MTOK;

    f32x4 acc[2][2];
#pragma unroll
    for (int i = 0; i < 2; ++i)
#pragma unroll
        for (int j = 0; j < 2; ++j) acc[i][j] = f32x4{0.f, 0.f, 0.f, 0.f};

    const int kd = tid & 63, kq = tid >> 6;   // ksum: row kd, slot pair kq
    float ksacc = 0.f;

    for (int st = 0; st < 4; ++st) {          // 4 x 64-token subtiles
        const int tb = tok0 + st * 64;
        __syncthreads();                      // prev tile reads done
#pragma unroll
        for (int i = 0; i < 2; ++i) {
            const int rb = (wv * 2 + i) * 8;
            gload16(&kvT[krow + (size_t)(rb + l8) * MTOK + tb + sslot], &kt[rb * 64]);
            gload16(&kvT[vrow + (size_t)(rb + l8) * MTOK + tb + sslot], &vt[rb * 64]);
        }
        __syncthreads();                      // vmcnt drain: tiles ready
#pragma unroll
        for (int ks = 0; ks < 2; ++ks) {
            const int soff = ((ks * 4 + kc) ^ sw) << 3;
            short8 af[2], bf[2];
#pragma unroll
            for (int mi = 0; mi < 2; ++mi)
                af[mi] = *reinterpret_cast<const short8*>(
                    &kt[(wr * 32 + mi * 16 + lr16) * 64 + soff]);
#pragma unroll
            for (int ni = 0; ni < 2; ++ni)
                bf[ni] = *reinterpret_cast<const short8*>(
                    &vt[(wc * 32 + ni * 16 + lr16) * 64 + soff]);
#pragma unroll
            for (int mi = 0; mi < 2; ++mi)
#pragma unroll
                for (int ni = 0; ni < 2; ++ni)
                    acc[mi][ni] = __builtin_amdgcn_mfma_f32_16x16x32_bf16(
                        af[mi], bf[ni], acc[mi][ni], 0, 0, 0);
        }
        // ksum: thread sums 16 tokens (2 slots) of k row kd
#pragma unroll
        for (int sl = 0; sl < 2; ++sl) {
            const int phys = (kq * 2 + sl) ^ (kd & 7);
            short8 v = *reinterpret_cast<const short8*>(&kt[kd * 64 + phys * 8]);
#pragma unroll
            for (int e = 0; e < 8; ++e) ksacc += bf2f((unsigned short)v[e]);
        }
    }
    ksr[kq][kd] = ksacc;
    __syncthreads();

    float* p = part + ((size_t)bh * NCH + ch) * 4160;
    const int orow = (ln >> 4) << 2;
    const int ocol = ln & 15;
#pragma unroll
    for (int mi = 0; mi < 2; ++mi)
#pragma unroll
        for (int ni = 0; ni < 2; ++ni) {
            const int d0 = wr * 32 + mi * 16 + orow;
            const int e  = wc * 32 + ni * 16 + ocol;
#pragma unroll
            for (int r = 0; r < 4; ++r)
                p[(d0 + r) * 64 + e] = acc[mi][ni][r];
        }
    if (tid < 64)
        p[4096 + tid] = ksr[0][tid] + ksr[1][tid] + ksr[2][tid] + ksr[3][tid];
}

// ---------------------------------------------------------------------------
// kv_reduce: sum partials; emit kvT split hi/lo bf16 (kvtb[bh][2][e][d]) and
// ksum fp32 (ksumf[bh][d]).
// ---------------------------------------------------------------------------
__global__ __launch_bounds__(256) void kv_reduce(
    const float* __restrict__ part, unsigned short* __restrict__ kvtb,
    float* __restrict__ ksumf)
{
    const int bh = blockIdx.x;
    for (int idx = threadIdx.x; idx < 4096; idx += 256) {
        float s = 0.f;
        for (int c = 0; c < NCH; ++c)
            s += part[((size_t)bh * NCH + c) * 4160 + idx];
        const int d = idx >> 6, e = idx & 63;
        const unsigned short hi = f2bf(s);
        const float lo = s - bf2f(hi);
        kvtb[(size_t)bh * 8192 + e * 64 + d] = hi;
        kvtb[(size_t)bh * 8192 + 4096 + e * 64 + d] = f2bf(lo);
    }
    if (threadIdx.x < 64) {
        float s = 0.f;
        for (int c = 0; c < NCH; ++c)
            s += part[((size_t)bh * NCH + c) * 4160 + 4096 + threadIdx.x];
        ksumf[bh * 64 + threadIdx.x] = s;
    }
}

// ---------------------------------------------------------------------------
// Phase B (MFMA): attn = (q_elu @ kv) / (q_elu . ksum + 1e-6), bf16 out.
// A = qbf [16384][1024] (already elu'd), staged swizzled per 256-token tile.
// B = kvtb hi/lo [64 e][64 d] per bh, read straight from global (L2-hot).
// den computed scalar fp32 (one thread per token).
// ---------------------------------------------------------------------------
__global__ __launch_bounds__(256) void attn_mfma(
    const unsigned short* __restrict__ qbf,
    const unsigned short* __restrict__ kvtb,
    const float* __restrict__ ksumf,
    unsigned short* __restrict__ attnbf)
{
    const int bh = blockIdx.x, tt = blockIdx.y;
    const int b = bh / H_, h = bh % H_;
    const int tok0 = b * N_ + tt * 256;

    __shared__ __align__(16) unsigned short qt[256 * 64];
    __shared__ float den[256];

    const int tid = threadIdx.x;
    const int wv = tid >> 6, ln = tid & 63;
    const int l8 = ln >> 3;
    const int sslot = ((ln & 7) ^ l8) << 3;
    const int lr16 = ln & 15;
    const int kc = ln >> 4;

    // B frags from global
    const unsigned short* kvb = kvtb + (size_t)bh * 8192;
    short8 bhf[4][2], blf[4][2];
#pragma unroll
    for (int n = 0; n < 4; ++n)
#pragma unroll
        for (int ks = 0; ks < 2; ++ks) {
            const int off = (n * 16 + lr16) * 64 + ks * 32 + kc * 8;
            bhf[n][ks] = *reinterpret_cast<const short8*>(&kvb[off]);
            blf[n][ks] = *reinterpret_cast<const short8*>(&kvb[4096 + off]);
        }

    // stage q tile: wave wv stages its own 64 rows
#pragma unroll
    for (int i = 0; i < 8; ++i) {
        const int rb = wv * 64 + i * 8;
        gload16(&qbf[(size_t)(tok0 + rb + l8) * INNER_ + h * 64 + sslot],
                &qt[rb * 64]);
    }

    // den: thread t <-> token t (fp32, exact from bf16 inputs)
    {
        float dsum = 0.f;
        const unsigned short* qr = &qbf[(size_t)(tok0 + tid) * INNER_ + h * 64];
        const float* ksp = &ksumf[bh * 64];
#pragma unroll
        for (int j = 0; j < 8; ++j) {
            short8 v = *reinterpret_cast<const short8*>(&qr[j * 8]);
#pragma unroll
            for (int e = 0; e < 8; ++e)
                dsum += bf2f((unsigned short)v[e]) * ksp[j * 8 + e];
        }
        den[tid] = dsum;
    }
    __syncthreads();   // drains gload16 + den visible

    f32x4 acc[4][4];
#pragma unroll
    for (int m = 0; m < 4; ++m)
#pragma unroll
        for (int n = 0; n < 4; ++n) acc[m][n] = f32x4{0.f, 0.f, 0.f, 0.f};

#pragma unroll
    for (int ks = 0; ks < 2; ++ks) {
        const int soff = ((ks * 4 + kc) ^ (lr16 & 7)) << 3;
        short8 af[4];
#pragma unroll
        for (int m = 0; m < 4; ++m)
            af[m] = *reinterpret_cast<const short8*>(
                &qt[(wv * 64 + m * 16 + lr16) * 64 + soff]);
#pragma unroll
        for (int m = 0; m < 4; ++m)
#pragma unroll
            for (int n = 0; n < 4; ++n) {
                acc[m][n] = __builtin_amdgcn_mfma_f32_16x16x32_bf16(
                    af[m], bhf[n][ks], acc[m][n], 0, 0, 0);
                acc[m][n] = __builtin_amdgcn_mfma_f32_16x16x32_bf16(
                    af[m], blf[n][ks], acc[m][n], 0, 0, 0);
            }
    }

    const int orow = (ln >> 4) << 2;
    const int ocol = ln & 15;
#pragma unroll
    for (int m = 0; m < 4; ++m) {
        const int rl = wv * 64 + m * 16 + orow;
#pragma unroll
        for (int r = 0; r < 4; ++r) {
            const float z = 1.f / (den[rl + r] + 1e-6f);
            const size_t orow_g = (size_t)(tok0 + rl + r) * INNER_ + h * 64;
#pragma unroll
            for (int n = 0; n < 4; ++n)
                attnbf[orow_g + n * 16 + ocol] = f2bf(acc[m][n][r] * z);
        }
    }
}

// ---------------------------------------------------------------------------
extern "C" void kernel_launch(void* const* d_in, const int* in_sizes, int n_in,
                              void* d_out, int out_size, void* d_ws, size_t ws_size,
                              hipStream_t stream)
{
    const float* x    = (const float*)d_in[0];
    const int*   mask = (const int*)d_in[1];
    const float* Wqkv = (const float*)d_in[2];
    const float* Wout = (const float*)d_in[3];
    const float* bout = (const float*)d_in[4];
    float* out = (float*)d_out;

    // Workspace layout (bytes, all 16B aligned):
    //  [0,        33554432)  attnbf bf16 [16384][1024]
    //  [33554432, 100663296) kvT  bf16 [2048][16384]  (masked, k-half elu'd)
    //  [100663296,106954752) WqkvT bf16 [3072][1024]
    //  [106954752,109051904) WoutT bf16 [1024][1024]
    //  [109051904,126091264) part fp32 [64][16][4160]
    //  [126091264,127139840) kvtb bf16 [64][2][64][64] (hi/lo split, [e][d])
    //  [127139840,127156224) ksumf fp32 [64][64]
    const size_t need = 127156224;
    if (ws_size < need) return;

    char* base = (char*)d_ws;
    unsigned short* attnbf = (unsigned short*)base;
    unsigned short* kvT    = (unsigned short*)(base + 33554432);
    unsigned short* wqkvT  = (unsigned short*)(base + 100663296);
    unsigned short* woutT  = (unsigned short*)(base + 106954752);
    float* part  = (float*)(base + 109051904);
    unsigned short* kvtb = (unsigned short*)(base + 126091264);
    float* ksumf = (float*)(base + 127139840);
    unsigned short* qbf = (unsigned short*)d_out;                // d_out scratch

    // prep: weight transposes only (x cast fused into GEMM1 A-staging)
    prep_w<<<dim3(4096), dim3(256), 0, stream>>>(Wqkv, wqkvT, Wout, woutT);

    // GEMM1 merged (N=3072), A = x fp32 (cast fused into staging):
    // cols 0..1023 -> qbf = elu1(.) bf16 (in d_out);
    // cols 1024..3071 -> kvT[ch][tok] transposed bf16 (mask, k-half elu'd)
    gemm256<3, 0, 1><<<dim3(64 * 12), dim3(512), 0, stream>>>(
        x, wqkvT, qbf, kvT, nullptr, mask,
        MTOK, QKVC, DIM_, DIM_, DIM_, 1024);

    // Phase A
    kv_partial<<<dim3(B_ * H_, NCH), dim3(256), 0, stream>>>(kvT, part);
    kv_reduce<<<dim3(B_ * H_), dim3(256), 0, stream>>>(part, kvtb, ksumf);

    // Phase B
    attn_mfma<<<dim3(B_ * H_, N_ / 256), dim3(256), 0, stream>>>(
        qbf, kvtb, ksumf, attnbf);

    // GEMM2: out = attn @ Wout + bout (fp32 out)
    gemm256<0, 1, 0><<<dim3(64 * 4), dim3(512), 0, stream>>>(
        attnbf, woutT, out, nullptr, bout, nullptr,
        MTOK, INNER_, INNER_, INNER_, INNER_, INNER_);
}

// Round 11
// 235.315 us; speedup vs baseline: 1.2519x; 1.2519x over previous
//
#include <hip/hip_runtime.h>
#include <hip/hip_bf16.h>
#include <cstddef>
#include <cstdint>

#define B_     4
#define N_     4096
#define DIM_   1024
#define H_     16
#define DH_    64
#define INNER_ 1024
#define MTOK   (B_ * N_)        // 16384
#define QKVC   (3 * INNER_)
#define NCH    16
#define CHUNK  (N_ / NCH)       // 256

typedef __attribute__((ext_vector_type(8))) short short8;   // 8 bf16 = 4 VGPR
typedef __attribute__((ext_vector_type(4))) float f32x4;    // MFMA acc

__device__ __forceinline__ float elu1(float x) {
    return x > 0.f ? x + 1.f : __expf(x);
}
__device__ __forceinline__ unsigned short f2bf(float f) {
    __hip_bfloat16 h = __float2bfloat16(f);
    return __builtin_bit_cast(unsigned short, h);
}
__device__ __forceinline__ float bf2f(unsigned short u) {
    __hip_bfloat16 h = __builtin_bit_cast(__hip_bfloat16, u);
    return __bfloat162float(h);
}

// async global->LDS, 16B per lane. LDS dest is wave-uniform base + lane*16;
// global source address is per-lane.
__device__ __forceinline__ void gload16(const void* g, void* l) {
    __builtin_amdgcn_global_load_lds(
        (const __attribute__((address_space(1))) unsigned int*)g,
        (__attribute__((address_space(3))) unsigned int*)l, 16, 0, 0);
}

// ---------------------------------------------------------------------------
// Fused prep: blocks 0..2047 cast x fp32->bf16; 2048..5119 transpose-cast
// Wqkv; 5120..6143 transpose-cast Wout. One launch instead of three.
// ---------------------------------------------------------------------------
__global__ __launch_bounds__(256) void prep_fused(
    const float* __restrict__ x, unsigned short* __restrict__ xbf,
    const float* __restrict__ Wqkv, unsigned short* __restrict__ wqkvT,
    const float* __restrict__ Wout, unsigned short* __restrict__ woutT)
{
    __shared__ float t[32][33];
    const int blk = blockIdx.x;
    if (blk < 2048) {
        const long n8 = (long)MTOK * DIM_ / 8;
        const long stride = 2048L * 256;
        for (long i = (long)blk * 256 + threadIdx.x; i < n8; i += stride) {
            const float4 f0 = reinterpret_cast<const float4*>(x)[2 * i];
            const float4 f1 = reinterpret_cast<const float4*>(x)[2 * i + 1];
            short8 u;
            u[0] = (short)f2bf(f0.x); u[1] = (short)f2bf(f0.y);
            u[2] = (short)f2bf(f0.z); u[3] = (short)f2bf(f0.w);
            u[4] = (short)f2bf(f1.x); u[5] = (short)f2bf(f1.y);
            u[6] = (short)f2bf(f1.z); u[7] = (short)f2bf(f1.w);
            reinterpret_cast<short8*>(xbf)[i] = u;
        }
        return;
    }
    const float* src; unsigned short* dst; int R, C, r0, c0;
    if (blk < 5120) {
        const int id = blk - 2048;               // 3072 tiles: 32 x 96
        src = Wqkv; dst = wqkvT; R = DIM_; C = QKVC;
        r0 = (id & 31) * 32; c0 = (id >> 5) * 32;
    } else {
        const int id = blk - 5120;               // 1024 tiles: 32 x 32
        src = Wout; dst = woutT; R = INNER_; C = INNER_;
        r0 = (id & 31) * 32; c0 = (id >> 5) * 32;
    }
    const int tx = threadIdx.x & 31, ty = threadIdx.x >> 5;   // ty 0..7
#pragma unroll
    for (int i = 0; i < 4; ++i)
        t[ty * 4 + i][tx] = src[(size_t)(r0 + ty * 4 + i) * C + c0 + tx];
    __syncthreads();
#pragma unroll
    for (int i = 0; i < 4; ++i)
        dst[(size_t)(c0 + ty * 4 + i) * R + r0 + tx] = f2bf(t[tx][ty * 4 + i]);
}

// ---------------------------------------------------------------------------
// bf16 MFMA GEMM, 256x256 tile / BK=64 / 8 waves (2Mx4N) / 4-phase K-tiles.
// C[M][N] = A[M][K] @ BT[N][K]^T.
// Round-5-verified structure (best measured): 128B LDS rows, 8x16B-slot XOR
// swizzle (phys = log^(row&7)), pre-swizzled global_load_lds source,
// conflict-free ds_read_b128; A-frag reads software-pipelined by phase
// parity; staging for t+1 issued at tile prologue; one __syncthreads()
// boundary per K-tile.
// EPI 0: fp32 out (+bias).   EPI 1: bf16 out, elu1 applied (q path).
// EPI 2: bf16 TRANSPOSED out dst[c][row], mask[row], elu1 iff c<1024 local.
// EPI 3: merged qkv (N=3072). col0 < 1024: q path -> Cv bf16 elu1 (ldc).
//        col0 >= 1024: kv path -> Ckv[ch][tok] transposed bf16 (ld MTOK),
//        mask[tok], elu1 iff global col < 2048 (k half); LDS-bounced.
// Requires M%256==0, N%256==0, K%64==0.
// ---------------------------------------------------------------------------
template<int EPI, int HAS_BIAS>
__global__ __launch_bounds__(512, 2) void gemm256(
    const unsigned short* __restrict__ A,   // [M][K] bf16
    const unsigned short* __restrict__ BT,  // [N][K] bf16
    void* __restrict__ Cv,
    unsigned short* __restrict__ Ckv,
    const float* __restrict__ bias,
    const int* __restrict__ msk,
    int M, int N, int K, int lda, int ldb, int ldc)
{
    // smem[0..1] = A double buffer, smem[2..3] = B double buffer.
    // EPI 2/3-kv reuse the whole 128 KiB as a 256x256 bf16 transpose bounce.
    __shared__ __align__(16) unsigned short smem[4][256 * 64];

    const int tid = threadIdx.x;
    const int wv  = tid >> 6;        // wave 0..7
    const int ln  = tid & 63;
    const int wr  = wv >> 2;         // 0..1  (M half)
    const int wc  = wv & 3;          // 0..3  (N quarter)

    // T1: bijective XCD-aware block swizzle (8 XCDs); per-XCD chunks are
    // contiguous in by-major order => same-A-panel blocks cluster per XCD.
    const int nwg = gridDim.x;
    int wg = blockIdx.x;
    {
        const int q = nwg >> 3, r = nwg & 7;
        const int xcd = wg & 7, lid = wg >> 3;
        wg = (xcd < r ? xcd * (q + 1) : r * (q + 1) + (xcd - r) * q) + lid;
    }
    const int ncol = N >> 8;
    const int bx = wg % ncol;
    const int by = wg / ncol;
    const int row0 = by << 8;
    const int col0 = bx << 8;

    // staging: lane l covers LDS row base+(l>>3), physical 16B slot (l&7);
    // physical slot s at row r holds logical slot s^(r&7).
    const int l8    = ln >> 3;
    const int sslot = ((ln & 7) ^ l8) << 3;   // bf16 col offset within BK=64

    const int lr16 = ln & 15;
    const int kc   = ln >> 4;
    const int sw   = lr16 & 7;
    const int soff0 = (kc ^ sw) << 3;          // ks=0 logical slot kc
    const int soff1 = ((4 + kc) ^ sw) << 3;    // ks=1 logical slot 4+kc

    f32x4 acc[8][4];
#pragma unroll
    for (int m = 0; m < 8; ++m)
#pragma unroll
        for (int n = 0; n < 4; ++n) acc[m][n] = f32x4{0.f, 0.f, 0.f, 0.f};

    const int NT = K >> 6;

    // prologue: stage K-tile 0 into buffer 0
#pragma unroll
    for (int i = 0; i < 4; ++i) {
        const int lr = wv * 32 + i * 8;
        gload16(&A [(size_t)(row0 + lr + l8) * lda + sslot], &smem[0][lr * 64]);
        gload16(&BT[(size_t)(col0 + lr + l8) * ldb + sslot], &smem[2][lr * 64]);
    }
    __syncthreads();   // vmcnt(0) drain + barrier: tile 0 resident

    for (int t = 0; t < NT; ++t) {
        const int cur = t & 1;
        const unsigned short* bufA = smem[cur];
        const unsigned short* bufB = smem[2 + cur];
        short8 bf[4][2];
        short8 af[2][2][2];   // [phase parity][mi][ks]

        // tile prologue: B-frags (held all tile), phase-0 A-frags, staging
#pragma unroll
        for (int n = 0; n < 4; ++n) {
            const int row = wc * 64 + n * 16 + lr16;
            bf[n][0] = *reinterpret_cast<const short8*>(&bufB[row * 64 + soff0]);
            bf[n][1] = *reinterpret_cast<const short8*>(&bufB[row * 64 + soff1]);
        }
#pragma unroll
        for (int mi = 0; mi < 2; ++mi) {
            const int row = wr * 128 + mi * 16 + lr16;
            af[0][mi][0] = *reinterpret_cast<const short8*>(&bufA[row * 64 + soff0]);
            af[0][mi][1] = *reinterpret_cast<const short8*>(&bufA[row * 64 + soff1]);
        }
        if (t + 1 < NT) {
            const int k0 = (t + 1) << 6;
            unsigned short* nA = smem[cur ^ 1];
            unsigned short* nB = smem[2 + (cur ^ 1)];
#pragma unroll
            for (int i = 0; i < 4; ++i) {
                const int lr = wv * 32 + i * 8;
                gload16(&A [(size_t)(row0 + lr + l8) * lda + k0 + sslot],
                        &nA[lr * 64]);
                gload16(&BT[(size_t)(col0 + lr + l8) * ldb + k0 + sslot],
                        &nB[lr * 64]);
            }
        }

#pragma unroll
        for (int p = 0; p < 4; ++p) {
            if (p > 0) __builtin_amdgcn_s_barrier();
            // prefetch next phase's A-frags BEFORE this phase's MFMA:
            // latency hides under the 16-MFMA cluster (compiler inserts
            // the counted lgkmcnt before first use next phase).
            if (p < 3) {
#pragma unroll
                for (int mi = 0; mi < 2; ++mi) {
                    const int row = wr * 128 + ((p + 1) * 2 + mi) * 16 + lr16;
                    af[(p + 1) & 1][mi][0] =
                        *reinterpret_cast<const short8*>(&bufA[row * 64 + soff0]);
                    af[(p + 1) & 1][mi][1] =
                        *reinterpret_cast<const short8*>(&bufA[row * 64 + soff1]);
                }
            }
            __builtin_amdgcn_s_setprio(1);
#pragma unroll
            for (int mi = 0; mi < 2; ++mi)
#pragma unroll
                for (int n = 0; n < 4; ++n) {
                    acc[p * 2 + mi][n] = __builtin_amdgcn_mfma_f32_16x16x32_bf16(
                        af[p & 1][mi][0], bf[n][0], acc[p * 2 + mi][n], 0, 0, 0);
                    acc[p * 2 + mi][n] = __builtin_amdgcn_mfma_f32_16x16x32_bf16(
                        af[p & 1][mi][1], bf[n][1], acc[p * 2 + mi][n], 0, 0, 0);
                }
            __builtin_amdgcn_s_setprio(0);
        }
        __syncthreads();   // boundary: drain staging (issued ~4 phases ago)
    }

    // epilogue: C/D layout col=lane&15, row=(lane>>4)*4+reg
    const int orow = (ln >> 4) << 2;
    const int ocol = ln & 15;

    const bool kvpath = (EPI == 2) || (EPI == 3 && col0 >= 1024);

    if (kvpath) {
        // ---- transposed bf16 out via LDS bounce ----
        // tb[ch][tok] 256x256 bf16, 16B-slot swizzle: phys16 = log16 ^ (ch&7)
        unsigned short* tb = &smem[0][0];
        const int kvbase = (EPI == 3) ? 1024 : 0;   // channel offset of col0
        const int klimit = (EPI == 3) ? 2048 : 1024;
#pragma unroll
        for (int m = 0; m < 8; ++m) {
            const int rrb = wr * 128 + m * 16 + orow;       // local token, %4==0
            const int4 m4 = *reinterpret_cast<const int4*>(&msk[row0 + rrb]);
            int mv[4] = { m4.x, m4.y, m4.z, m4.w };
            const int slot16 = rrb >> 3, half = (rrb >> 2) & 1;
#pragma unroll
            for (int n = 0; n < 4; ++n) {
                const int chl = wc * 64 + n * 16 + ocol;    // local channel
                const bool isk = (col0 + chl) < klimit;
                ushort4 st;
#pragma unroll
                for (int r2 = 0; r2 < 4; ++r2) {
                    float o = acc[m][n][r2];
                    o = mv[r2] ? (isk ? elu1(o) : o) : 0.f;
                    ((unsigned short*)&st)[r2] = f2bf(o);
                }
                *reinterpret_cast<ushort4*>(
                    &tb[chl * 256 + ((slot16 ^ (chl & 7)) << 3) + half * 4]) = st;
            }
        }
        __syncthreads();
        unsigned short* dst = (EPI == 3) ? Ckv : (unsigned short*)Cv;
        const int ldt = (EPI == 3) ? MTOK : ldc;
#pragma unroll
        for (int i = 0; i < 16; ++i) {
            const int idx = i * 512 + tid;      // 8192 16B slots
            const int ch = idx >> 5;
            const int sl = idx & 31;
            const short8 v = *reinterpret_cast<const short8*>(
                &tb[ch * 256 + ((sl ^ (ch & 7)) << 3)]);
            *reinterpret_cast<short8*>(
                &dst[(size_t)(col0 - kvbase + ch) * ldt + row0 + sl * 8]) = v;
        }
    } else {
#pragma unroll
        for (int m = 0; m < 8; ++m) {
            const int rrb = row0 + wr * 128 + m * 16 + orow;
#pragma unroll
            for (int n = 0; n < 4; ++n) {
                const int c = col0 + wc * 64 + n * 16 + ocol;
                float bv = 0.f;
                if constexpr (HAS_BIAS) bv = bias[c];
#pragma unroll
                for (int r2 = 0; r2 < 4; ++r2) {
                    const int rr = rrb + r2;
                    float o = acc[m][n][r2] + bv;
                    if constexpr (EPI == 1 || EPI == 3) {
                        o = elu1(o);
                        ((unsigned short*)Cv)[(size_t)rr * ldc + c] = f2bf(o);
                    } else {
                        ((float*)Cv)[(size_t)rr * ldc + c] = o;
                    }
                }
            }
        }
    }
}

// ---------------------------------------------------------------------------
// Phase A (MFMA): per (b,h,chunk) partial kv[64][64] and ksum[64].
// Inputs already elu'd (k) and masked (k,v), in kvT [2048 ch][16384 tok] bf16:
// k channel = h*64+d, v channel = 1024+h*64+e.
// ---------------------------------------------------------------------------
__global__ __launch_bounds__(256) void kv_partial(
    const unsigned short* __restrict__ kvT, float* __restrict__ part)
{
    const int bh = blockIdx.x;        // 0..63
    const int ch = blockIdx.y;        // 0..15
    const int b = bh / H_, h = bh % H_;
    const int tok0 = b * N_ + ch * CHUNK;

    __shared__ __align__(16) unsigned short kt[64 * 64];
    __shared__ __align__(16) unsigned short vt[64 * 64];
    __shared__ float ksr[4][64];

    const int tid = threadIdx.x;
    const int wv = tid >> 6, ln = tid & 63;
    const int wr = wv >> 1, wc = wv & 1;      // 2x2 quadrants of 64x64
    const int l8 = ln >> 3;
    const int sslot = ((ln & 7) ^ l8) << 3;
    const int lr16 = ln & 15;
    const int kc = ln >> 4;
    const int sw = lr16 & 7;

    const size_t krow = (size_t)(h * 64) * MTOK;
    const size_t vrow = (size_t)(1024 + h * 64) * MTOK;

    f32x4 acc[2][2];
#pragma unroll
    for (int i = 0; i < 2; ++i)
#pragma unroll
        for (int j = 0; j < 2; ++j) acc[i][j] = f32x4{0.f, 0.f, 0.f, 0.f};

    const int kd = tid & 63, kq = tid >> 6;   // ksum: row kd, slot pair kq
    float ksacc = 0.f;

    for (int st = 0; st < 4; ++st) {          // 4 x 64-token subtiles
        const int tb = tok0 + st * 64;
        __syncthreads();                      // prev tile reads done
#pragma unroll
        for (int i = 0; i < 2; ++i) {
            const int rb = (wv * 2 + i) * 8;
            gload16(&kvT[krow + (size_t)(rb + l8) * MTOK + tb + sslot], &kt[rb * 64]);
            gload16(&kvT[vrow + (size_t)(rb + l8) * MTOK + tb + sslot], &vt[rb * 64]);
        }
        __syncthreads();                      // vmcnt drain: tiles ready
#pragma unroll
        for (int ks = 0; ks < 2; ++ks) {
            const int soff = ((ks * 4 + kc) ^ sw) << 3;
            short8 af[2], bf[2];
#pragma unroll
            for (int mi = 0; mi < 2; ++mi)
                af[mi] = *reinterpret_cast<const short8*>(
                    &kt[(wr * 32 + mi * 16 + lr16) * 64 + soff]);
#pragma unroll
            for (int ni = 0; ni < 2; ++ni)
                bf[ni] = *reinterpret_cast<const short8*>(
                    &vt[(wc * 32 + ni * 16 + lr16) * 64 + soff]);
#pragma unroll
            for (int mi = 0; mi < 2; ++mi)
#pragma unroll
                for (int ni = 0; ni < 2; ++ni)
                    acc[mi][ni] = __builtin_amdgcn_mfma_f32_16x16x32_bf16(
                        af[mi], bf[ni], acc[mi][ni], 0, 0, 0);
        }
        // ksum: thread sums 16 tokens (2 slots) of k row kd
#pragma unroll
        for (int sl = 0; sl < 2; ++sl) {
            const int phys = (kq * 2 + sl) ^ (kd & 7);
            short8 v = *reinterpret_cast<const short8*>(&kt[kd * 64 + phys * 8]);
#pragma unroll
            for (int e = 0; e < 8; ++e) ksacc += bf2f((unsigned short)v[e]);
        }
    }
    ksr[kq][kd] = ksacc;
    __syncthreads();

    float* p = part + ((size_t)bh * NCH + ch) * 4160;
    const int orow = (ln >> 4) << 2;
    const int ocol = ln & 15;
#pragma unroll
    for (int mi = 0; mi < 2; ++mi)
#pragma unroll
        for (int ni = 0; ni < 2; ++ni) {
            const int d0 = wr * 32 + mi * 16 + orow;
            const int e  = wc * 32 + ni * 16 + ocol;
#pragma unroll
            for (int r = 0; r < 4; ++r)
                p[(d0 + r) * 64 + e] = acc[mi][ni][r];
        }
    if (tid < 64)
        p[4096 + tid] = ksr[0][tid] + ksr[1][tid] + ksr[2][tid] + ksr[3][tid];
}

// ---------------------------------------------------------------------------
// kv_reduce: sum partials; emit kvT split hi/lo bf16 (kvtb[bh][2][e][d]) and
// ksum fp32 (ksumf[bh][d]).
// ---------------------------------------------------------------------------
__global__ __launch_bounds__(256) void kv_reduce(
    const float* __restrict__ part, unsigned short* __restrict__ kvtb,
    float* __restrict__ ksumf)
{
    const int bh = blockIdx.x;
    for (int idx = threadIdx.x; idx < 4096; idx += 256) {
        float s = 0.f;
        for (int c = 0; c < NCH; ++c)
            s += part[((size_t)bh * NCH + c) * 4160 + idx];
        const int d = idx >> 6, e = idx & 63;
        const unsigned short hi = f2bf(s);
        const float lo = s - bf2f(hi);
        kvtb[(size_t)bh * 8192 + e * 64 + d] = hi;
        kvtb[(size_t)bh * 8192 + 4096 + e * 64 + d] = f2bf(lo);
    }
    if (threadIdx.x < 64) {
        float s = 0.f;
        for (int c = 0; c < NCH; ++c)
            s += part[((size_t)bh * NCH + c) * 4160 + 4096 + threadIdx.x];
        ksumf[bh * 64 + threadIdx.x] = s;
    }
}

// ---------------------------------------------------------------------------
// Phase B (MFMA): attn = (q_elu @ kv) / (q_elu . ksum + 1e-6), bf16 out.
// A = qbf [16384][1024] (already elu'd), staged swizzled per 256-token tile.
// B = kvtb hi/lo [64 e][64 d] per bh, read straight from global (L2-hot).
// den computed scalar fp32 (one thread per token).
// ---------------------------------------------------------------------------
__global__ __launch_bounds__(256) void attn_mfma(
    const unsigned short* __restrict__ qbf,
    const unsigned short* __restrict__ kvtb,
    const float* __restrict__ ksumf,
    unsigned short* __restrict__ attnbf)
{
    const int bh = blockIdx.x, tt = blockIdx.y;
    const int b = bh / H_, h = bh % H_;
    const int tok0 = b * N_ + tt * 256;

    __shared__ __align__(16) unsigned short qt[256 * 64];
    __shared__ float den[256];

    const int tid = threadIdx.x;
    const int wv = tid >> 6, ln = tid & 63;
    const int l8 = ln >> 3;
    const int sslot = ((ln & 7) ^ l8) << 3;
    const int lr16 = ln & 15;
    const int kc = ln >> 4;

    // B frags from global
    const unsigned short* kvb = kvtb + (size_t)bh * 8192;
    short8 bhf[4][2], blf[4][2];
#pragma unroll
    for (int n = 0; n < 4; ++n)
#pragma unroll
        for (int ks = 0; ks < 2; ++ks) {
            const int off = (n * 16 + lr16) * 64 + ks * 32 + kc * 8;
            bhf[n][ks] = *reinterpret_cast<const short8*>(&kvb[off]);
            blf[n][ks] = *reinterpret_cast<const short8*>(&kvb[4096 + off]);
        }

    // stage q tile: wave wv stages its own 64 rows
#pragma unroll
    for (int i = 0; i < 8; ++i) {
        const int rb = wv * 64 + i * 8;
        gload16(&qbf[(size_t)(tok0 + rb + l8) * INNER_ + h * 64 + sslot],
                &qt[rb * 64]);
    }

    // den: thread t <-> token t (fp32, exact from bf16 inputs)
    {
        float dsum = 0.f;
        const unsigned short* qr = &qbf[(size_t)(tok0 + tid) * INNER_ + h * 64];
        const float* ksp = &ksumf[bh * 64];
#pragma unroll
        for (int j = 0; j < 8; ++j) {
            short8 v = *reinterpret_cast<const short8*>(&qr[j * 8]);
#pragma unroll
            for (int e = 0; e < 8; ++e)
                dsum += bf2f((unsigned short)v[e]) * ksp[j * 8 + e];
        }
        den[tid] = dsum;
    }
    __syncthreads();   // drains gload16 + den visible

    f32x4 acc[4][4];
#pragma unroll
    for (int m = 0; m < 4; ++m)
#pragma unroll
        for (int n = 0; n < 4; ++n) acc[m][n] = f32x4{0.f, 0.f, 0.f, 0.f};

#pragma unroll
    for (int ks = 0; ks < 2; ++ks) {
        const int soff = ((ks * 4 + kc) ^ (lr16 & 7)) << 3;
        short8 af[4];
#pragma unroll
        for (int m = 0; m < 4; ++m)
            af[m] = *reinterpret_cast<const short8*>(
                &qt[(wv * 64 + m * 16 + lr16) * 64 + soff]);
#pragma unroll
        for (int m = 0; m < 4; ++m)
#pragma unroll
            for (int n = 0; n < 4; ++n) {
                acc[m][n] = __builtin_amdgcn_mfma_f32_16x16x32_bf16(
                    af[m], bhf[n][ks], acc[m][n], 0, 0, 0);
                acc[m][n] = __builtin_amdgcn_mfma_f32_16x16x32_bf16(
                    af[m], blf[n][ks], acc[m][n], 0, 0, 0);
            }
    }

    const int orow = (ln >> 4) << 2;
    const int ocol = ln & 15;
#pragma unroll
    for (int m = 0; m < 4; ++m) {
        const int rl = wv * 64 + m * 16 + orow;
#pragma unroll
        for (int r = 0; r < 4; ++r) {
            const float z = 1.f / (den[rl + r] + 1e-6f);
            const size_t orow_g = (size_t)(tok0 + rl + r) * INNER_ + h * 64;
#pragma unroll
            for (int n = 0; n < 4; ++n)
                attnbf[orow_g + n * 16 + ocol] = f2bf(acc[m][n][r] * z);
        }
    }
}

// ---------------------------------------------------------------------------
extern "C" void kernel_launch(void* const* d_in, const int* in_sizes, int n_in,
                              void* d_out, int out_size, void* d_ws, size_t ws_size,
                              hipStream_t stream)
{
    const float* x    = (const float*)d_in[0];
    const int*   mask = (const int*)d_in[1];
    const float* Wqkv = (const float*)d_in[2];
    const float* Wout = (const float*)d_in[3];
    const float* bout = (const float*)d_in[4];
    float* out = (float*)d_out;

    // Workspace layout (bytes, all 16B aligned):
    //  [0,        33554432)  xbf  bf16 [16384][1024]   (later aliased by attnbf)
    //  [33554432, 100663296) kvT  bf16 [2048][16384]  (masked, k-half elu'd)
    //  [100663296,106954752) WqkvT bf16 [3072][1024]
    //  [106954752,109051904) WoutT bf16 [1024][1024]
    //  [109051904,126091264) part fp32 [64][16][4160]
    //  [126091264,127139840) kvtb bf16 [64][2][64][64] (hi/lo split, [e][d])
    //  [127139840,127156224) ksumf fp32 [64][64]
    const size_t need = 127156224;
    if (ws_size < need) return;

    char* base = (char*)d_ws;
    unsigned short* xbf    = (unsigned short*)base;
    unsigned short* attnbf = xbf;                                // alias
    unsigned short* kvT    = (unsigned short*)(base + 33554432);
    unsigned short* wqkvT  = (unsigned short*)(base + 100663296);
    unsigned short* woutT  = (unsigned short*)(base + 106954752);
    float* part  = (float*)(base + 109051904);
    unsigned short* kvtb = (unsigned short*)(base + 126091264);
    float* ksumf = (float*)(base + 127139840);
    unsigned short* qbf = (unsigned short*)d_out;                // d_out scratch

    // prep: cast + both weight transposes, one launch
    prep_fused<<<dim3(6144), dim3(256), 0, stream>>>(
        x, xbf, Wqkv, wqkvT, Wout, woutT);

    // GEMM1 merged (N=3072): cols 0..1023 -> qbf = elu1(.) bf16 (in d_out);
    // cols 1024..3071 -> kvT[ch][tok] transposed bf16 (mask, k-half elu'd)
    gemm256<3, 0><<<dim3(64 * 12), dim3(512), 0, stream>>>(
        xbf, wqkvT, qbf, kvT, nullptr, mask,
        MTOK, QKVC, DIM_, DIM_, DIM_, 1024);

    // Phase A
    kv_partial<<<dim3(B_ * H_, NCH), dim3(256), 0, stream>>>(kvT, part);
    kv_reduce<<<dim3(B_ * H_), dim3(256), 0, stream>>>(part, kvtb, ksumf);

    // Phase B (overwrites xbf region with attn bf16)
    attn_mfma<<<dim3(B_ * H_, N_ / 256), dim3(256), 0, stream>>>(
        qbf, kvtb, ksumf, attnbf);

    // GEMM2: out = attn @ Wout + bout (fp32 out)
    gemm256<0, 1><<<dim3(64 * 4), dim3(512), 0, stream>>>(
        attnbf, woutT, out, nullptr, bout, nullptr,
        MTOK, INNER_, INNER_, INNER_, INNER_, INNER_);
}